// Round 5
// baseline (1313.999 us; speedup 1.0000x reference)
//
#include <hip/hip_runtime.h>
#include <hip/hip_bf16.h>
#include <math.h>

#define L_  6
#define D_  384
#define NH_ 6
#define HD_ 64
#define HF_ 768
#define V_  4096
#define B_  4
#define T_  2048
#define BT_ (B_*T_)

typedef unsigned short u16;
typedef __attribute__((ext_vector_type(8))) short short8;
typedef __attribute__((ext_vector_type(4))) float f32x4;

__device__ __forceinline__ float bf2f(u16 u){
  union { unsigned int i; float f; } c; c.i = ((unsigned int)u)<<16; return c.f;
}
__device__ __forceinline__ u16 f2bf(float f){
  union { float f; unsigned int i; } c; c.f = f;
  unsigned int x = c.i;
  x += 0x7fffu + ((x>>16)&1u);
  return (u16)(x>>16);
}
__device__ __forceinline__ f32x4 mfma16(short8 a, short8 b, f32x4 c){
  return __builtin_amdgcn_mfma_f32_16x16x32_bf16(a,b,c,0,0,0);
}
// 16-lane max reduce on the VALU pipe (no ds_bpermute): xor1, xor2, xor7, xor15
template<int CTRL>
__device__ __forceinline__ float dppmax(float x){
  int v = __builtin_amdgcn_update_dpp(0, __builtin_bit_cast(int, x), CTRL, 0xf, 0xf, true);
  return fmaxf(x, __builtin_bit_cast(float, v));
}
__device__ __forceinline__ float rowmax16(float x){
  x = dppmax<0xB1>(x);   // quad_perm [1,0,3,2]  : xor 1
  x = dppmax<0x4E>(x);   // quad_perm [2,3,0,1]  : xor 2
  x = dppmax<0x141>(x);  // row_half_mirror      : xor 7
  x = dppmax<0x140>(x);  // row_mirror           : xor 15
  return x;
}
// async global->LDS, 16B per lane, LDS dest = base + lane*16 (wave-uniform base)
#define GLD16(gp, lp) __builtin_amdgcn_global_load_lds( \
    (const __attribute__((address_space(1))) void*)(gp), \
    (__attribute__((address_space(3))) void*)(lp), 16, 0, 0)

// ---------------- embedding gather ----------------
__global__ void embed_kernel(const int* __restrict__ x, const float* __restrict__ emb,
                             float* __restrict__ h){
  const int idx = blockIdx.x*256 + threadIdx.x;
  if(idx >= BT_*D_) return;
  const int t = idx / D_;
  const int d = idx - t*D_;
  h[idx] = emb[(size_t)x[t]*D_ + d];
}

// ---- coalesced LDS-tiled weight transpose+cast: dst[b][n][k]=bf16(src[b][k][n])
__global__ __launch_bounds__(256) void wtrans_kernel(const float* __restrict__ src,
    u16* __restrict__ dst, int K, int N, size_t srcBatch, size_t dstBatch){
  __shared__ float tile[32][33];
  src += (size_t)blockIdx.z*srcBatch;
  dst += (size_t)blockIdx.z*dstBatch;
  const int tx = threadIdx.x&31, ty = threadIdx.x>>5;
  const int n0 = blockIdx.x*32, k0 = blockIdx.y*32;
  #pragma unroll
  for(int j=0;j<4;j++)
    tile[ty+j*8][tx] = src[(size_t)(k0+ty+j*8)*N + n0+tx];
  __syncthreads();
  #pragma unroll
  for(int j=0;j<4;j++)
    dst[(size_t)(n0+ty+j*8)*K + k0+tx] = f2bf(tile[tx][ty+j*8]);
}

// ---------------- rmsnorm: one wave per row of 384 ----------------
__global__ __launch_bounds__(256) void rms_kernel(const float* __restrict__ h,
                                                  const float* __restrict__ w,
                                                  u16* __restrict__ out){
  const int wave = threadIdx.x>>6, lane = threadIdx.x&63;
  const size_t row = (size_t)blockIdx.x*4 + wave;
  const float* hr = h + row*D_;
  float v[6]; float ss = 0.f;
  #pragma unroll
  for(int i=0;i<6;i++){ v[i] = hr[lane + i*64]; ss += v[i]*v[i]; }
  #pragma unroll
  for(int o=1;o<64;o<<=1) ss += __shfl_xor(ss, o);
  const float rn = rsqrtf(ss*(1.f/D_) + 1e-6f);
  u16* orow = out + row*D_;
  #pragma unroll
  for(int i=0;i<6;i++) orow[lane+i*64] = f2bf(v[i]*rn*w[lane+i*64]);
}

// ---------------- MFMA GEMM: C[M,N] = A[M,K] @ Wt[N,K]^T ----------------
// BM=128 rows/block, BN in {128,64}. BK=64, double-buffered global_load_lds
// staging into XOR-swizzled LDS: prefetch tile t+1 issued before computing
// tile t, counted s_waitcnt vmcnt(8/6), raw s_barriers. MODE: 0=f32 out,
// 1=bias+gelu bf16, 2=f32 resid +=, 3=QKV split (v transposed to
// [B,NH,HD,T]), 4=resid += AND copy to fout2 (mid output fusion).
template<int MODE, int K, int BN>
__global__ __launch_bounds__(256) void gemm_kernel(
    const u16* __restrict__ A, const u16* __restrict__ Wt, int N,
    const float* __restrict__ bias, u16* __restrict__ out, float* __restrict__ fout,
    u16* __restrict__ qo, u16* __restrict__ ko, u16* __restrict__ vo,
    float* __restrict__ fout2)
{
  __shared__ u16 As[2][128*64];
  __shared__ u16 Bs[2][BN*64];
  const int w = threadIdx.x>>6, lane = threadIdx.x&63;
  const int l16 = lane&15, quad = lane>>4;
  const int r0 = blockIdx.y*128, n0 = blockIdx.x*BN;
  const int mst = lane>>3;                 // row within 1KB wave-chunk (8 rows)
  const int cst = (lane&7) ^ (lane>>3);    // swizzled 16B-chunk index

  constexpr int MI = (BN==128) ? 4 : 2;
  constexpr int NKT = K/64;
  const int wrow = (BN==128) ? (w&1)*64 : w*32;   // wave row base in tile
  const int wcol = (BN==128) ? (w>>1)*64 : 0;     // wave col base in tile

  f32x4 acc[MI][4];
  #pragma unroll
  for(int mi=0;mi<MI;mi++)
    #pragma unroll
    for(int ni=0;ni<4;ni++){ acc[mi][ni][0]=0.f; acc[mi][ni][1]=0.f; acc[mi][ni][2]=0.f; acc[mi][ni][3]=0.f; }

  auto stage = [&](int kt, int bu){
    const int k0 = kt*64;
    #pragma unroll
    for(int i=0;i<4;i++){
      const int m = (w*4+i)*8 + mst;       // 0..127
      GLD16(A + (size_t)(r0+m)*K + k0 + cst*8, &As[bu][(w*4+i)*512]);
    }
    if constexpr(BN==128){
      #pragma unroll
      for(int i=0;i<4;i++){
        const int n = (w*4+i)*8 + mst;
        GLD16(Wt + (size_t)(n0+n)*K + k0 + cst*8, &Bs[bu][(w*4+i)*512]);
      }
    } else {
      #pragma unroll
      for(int i=0;i<2;i++){
        const int n = (w*2+i)*8 + mst;     // 0..63
        GLD16(Wt + (size_t)(n0+n)*K + k0 + cst*8, &Bs[bu][(w*2+i)*512]);
      }
    }
  };

  stage(0, 0);                             // prologue
  for(int kt=0; kt<NKT; kt++){
    const u16* Ac = As[kt&1];
    const u16* Bc = Bs[kt&1];
    if(kt+1 < NKT){
      stage(kt+1, (kt+1)&1);               // prefetch: lands under compute
      if constexpr(BN==128) asm volatile("s_waitcnt vmcnt(8)" ::: "memory");
      else                  asm volatile("s_waitcnt vmcnt(6)" ::: "memory");
    } else {
      asm volatile("s_waitcnt vmcnt(0)" ::: "memory");
    }
    __builtin_amdgcn_s_barrier();          // raw: no vmcnt(0) drain
    asm volatile("" ::: "memory");

    __builtin_amdgcn_s_setprio(1);
    #pragma unroll
    for(int ks=0;ks<2;ks++){
      short8 av[MI], bv[4];
      #pragma unroll
      for(int mi=0;mi<MI;mi++){
        const int m = wrow + mi*16 + l16;
        av[mi] = *(const short8*)&Ac[m*64 + (((ks*4+quad)^(l16&7))*8)];
      }
      #pragma unroll
      for(int ni=0;ni<4;ni++){
        const int n = wcol + ni*16 + l16;
        bv[ni] = *(const short8*)&Bc[n*64 + (((ks*4+quad)^(l16&7))*8)];
      }
      #pragma unroll
      for(int mi=0;mi<MI;mi++)
        #pragma unroll
        for(int ni=0;ni<4;ni++)
          acc[mi][ni] = mfma16(av[mi], bv[ni], acc[mi][ni]);
    }
    __builtin_amdgcn_s_setprio(0);
    if(kt+1 < NKT){
      asm volatile("" ::: "memory");
      __builtin_amdgcn_s_barrier();        // all waves done reading buf kt&1
    }
  }

  #pragma unroll
  for(int mi=0;mi<MI;mi++){
    #pragma unroll
    for(int ni=0;ni<4;ni++){
      const int col = n0 + wcol + ni*16 + l16;
      #pragma unroll
      for(int r=0;r<4;r++){
        const int row = r0 + wrow + mi*16 + quad*4 + r;
        float v = acc[mi][ni][r];
        if(MODE==0){
          fout[(size_t)row*N + col] = v;
        } else if(MODE==1){
          v += bias[col];
          v = 0.5f*v*(1.f + erff(v*0.70710678118f));
          out[(size_t)row*N + col] = f2bf(v);
        } else if(MODE==2){
          if(bias) v += bias[col];
          fout[(size_t)row*N + col] += v;
        } else if(MODE==4){
          v += bias[col];
          const float nv = fout[(size_t)row*N + col] + v;
          fout[(size_t)row*N + col] = nv;
          fout2[(size_t)row*N + col] = nv;
        } else {
          if(col < D_)        qo[(size_t)row*D_ + col]      = f2bf(v);
          else if(col < 2*D_) ko[(size_t)row*D_ + (col-D_)] = f2bf(v);
          else {
            const int cv = col - 2*D_;
            const int hh = cv>>6, dd = cv&63;
            const int bb = row>>11, tt = row&(T_-1);
            vo[(((size_t)(bb*NH_+hh))*HD_ + dd)*T_ + tt] = f2bf(v);
          }
        }
      }
    }
  }
}

// ---------------- causal flash attention ----------------
// grid (T/128, B*NH), 4 waves, 32 q rows/wave (2 row-groups of 16), KT=64
// k-tiles. Per-tile fixed costs (staging, 2 barriers, K/V LDS reads) are
// amortized over 2x the MFMA vs the 64-q version: K/V fragments read once,
// used by both row-groups. Double-buffered K/V, counted vmcnt(4), raw
// s_barriers (no vmcnt(0) mid-loop). LDS = 53248 B. Row-sum free via
// ones-column in V^T (o[rg][4]); row-max via DPP; T13 defer-max.
// Fully-masked tiles (waves 0/1 at their last tile) skip compute.
__global__ __launch_bounds__(256) void flash_kernel(const u16* __restrict__ q,
    const u16* __restrict__ k, const u16* __restrict__ vt, u16* __restrict__ ao){
  __shared__ u16 Ks[2][64*64];               // [buf][k][d]   8KB each
  __shared__ u16 Vs[2][80*64];               // [buf][d][k]  10KB each; rows 64..79 static
  __shared__ __align__(16) u16 Pb[4][32*64]; // per-wave P    4KB each
  const int tid = threadIdx.x;
  const int w = tid>>6, lane = tid&63;
  const int l16 = lane&15, quad = lane>>4;
  const int bh = blockIdx.y, b = bh/NH_, h = bh - b*NH_;
  const int qt = (gridDim.x-1) - blockIdx.x; // reversed: heavy blocks first
  const int qw = qt*128 + w*32;              // wave's 32 q rows

  // init static V^T rows (row 64 = 1.0 -> PV computes row-sums in o[rg][4];
  // rows 65..79 = 0). Written once per buffer, DMA never touches them.
  {
    const int idx0 = tid*8;
    #pragma unroll
    for(int i=0;i<8;i++){
      const int idx = idx0 + i;              // 0..2047
      const int bu = idx>>10, rem = idx&1023;
      Vs[bu][(64 + (rem>>6))*64 + (rem&63)] = ((rem>>6)==0) ? (u16)0x3F80 : (u16)0;
    }
  }
  __syncthreads();

  short8 qf[2][2];
  #pragma unroll
  for(int rg=0;rg<2;rg++){
    const u16* qp = q + ((size_t)(b*T_ + qw + rg*16 + l16))*D_ + h*HD_ + quad*8;
    qf[rg][0] = *(const short8*)(qp);
    qf[rg][1] = *(const short8*)(qp + 32);
  }

  const u16* kbase = k + (size_t)(b*T_)*D_ + h*HD_;
  const u16* vbase = vt + (size_t)(b*NH_ + h)*HD_*T_;
  u16* Pw = &Pb[w][0];

  const int srow = lane>>3;            // row within 8-row 1KB chunk
  const int schunk = lane&7;           // dest 16B-chunk position in row
  const int kgc = schunk ^ srow;       // swizzled global source chunk

  float m[2][4];
  f32x4 o[2][5];                       // o[rg][4] = running sum(exp) column
  #pragma unroll
  for(int rg=0;rg<2;rg++){
    #pragma unroll
    for(int r=0;r<4;r++) m[rg][r] = -1e30f;
    #pragma unroll
    for(int c=0;c<5;c++){ o[rg][c][0]=0.f; o[rg][c][1]=0.f; o[rg][c][2]=0.f; o[rg][c][3]=0.f; }
  }

  const int nkt = 2*qt + 2;            // 64-wide tiles covering k <= qt*128+127

  // prologue: stage tile 0 into buffer 0 (4 loads/wave: 2 K + 2 V)
  #pragma unroll
  for(int i=0;i<2;i++){
    const int j = w*2+i;
    GLD16(kbase + (size_t)(j*8 + srow)*D_ + kgc*8, &Ks[0][j*512]);
  }
  #pragma unroll
  for(int i=0;i<2;i++){
    const int j = w*2+i;
    GLD16(vbase + (size_t)(j*8 + srow)*T_ + (schunk^srow)*8, &Vs[0][j*512]);
  }

  for(int kt=0; kt<nkt; kt++){
    const u16* Kc = Ks[kt&1];
    const u16* Vc = Vs[kt&1];
    if(kt+1 < nkt){
      // prefetch next tile into the other buffer (T14: issue-early)
      const int kb2 = (kt+1)*64;
      #pragma unroll
      for(int i=0;i<2;i++){
        const int j = w*2+i;
        GLD16(kbase + (size_t)(kb2 + j*8 + srow)*D_ + kgc*8, &Ks[(kt+1)&1][j*512]);
      }
      #pragma unroll
      for(int i=0;i<2;i++){
        const int j = w*2+i;
        GLD16(vbase + (size_t)(j*8 + srow)*T_ + kb2 + (schunk^srow)*8, &Vs[(kt+1)&1][j*512]);
      }
      // wait only this tile's 4 loads; the 4 prefetch loads stay in flight
      asm volatile("s_waitcnt vmcnt(4)" ::: "memory");
    } else {
      asm volatile("s_waitcnt vmcnt(0)" ::: "memory");
    }
    __builtin_amdgcn_s_barrier();      // raw: no vmcnt(0) drain

    const int kb = kt*64;
    if(kb <= qw + 31){                 // skip fully-masked tiles (wave-uniform)
      // ---- QK^T: K frags read once, used by both row-groups ----
      float s[2][4][4];
      __builtin_amdgcn_s_setprio(1);
      #pragma unroll
      for(int c=0;c<4;c++){
        const int krow = c*16 + l16;
        short8 kf0 = *(const short8*)&Kc[krow*64 + ((quad^(l16&7))*8)];
        short8 kf1 = *(const short8*)&Kc[krow*64 + (((4+quad)^(l16&7))*8)];
        #pragma unroll
        for(int rg=0;rg<2;rg++){
          f32x4 sa = {0.f,0.f,0.f,0.f};
          sa = mfma16(qf[rg][0], kf0, sa);
          sa = mfma16(qf[rg][1], kf1, sa);
          #pragma unroll
          for(int r=0;r<4;r++) s[rg][c][r] = sa[r]*0.125f;
        }
      }
      __builtin_amdgcn_s_setprio(0);
      // ---- causal mask (any tile overlapping the wave's diagonal) ----
      if(kb + 63 > qw){
        #pragma unroll
        for(int rg=0;rg<2;rg++)
          #pragma unroll
          for(int c=0;c<4;c++){
            const int kpos = kb + c*16 + l16;
            #pragma unroll
            for(int r=0;r<4;r++)
              if(kpos > qw + rg*16 + quad*4 + r) s[rg][c][r] = -1e30f;
          }
      }
      // ---- row max (DPP, VALU pipe) + deferred rescale ----
      float tmr[2][4];
      #pragma unroll
      for(int rg=0;rg<2;rg++)
        #pragma unroll
        for(int r=0;r<4;r++){
          float tm = fmaxf(fmaxf(s[rg][0][r], s[rg][1][r]), fmaxf(s[rg][2][r], s[rg][3][r]));
          tmr[rg][r] = rowmax16(tm);
        }
      float need = -1e30f;
      #pragma unroll
      for(int rg=0;rg<2;rg++)
        #pragma unroll
        for(int r=0;r<4;r++) need = fmaxf(need, tmr[rg][r] - m[rg][r]);
      if(!__all(need <= 8.f)){
        #pragma unroll
        for(int rg=0;rg<2;rg++)
          #pragma unroll
          for(int r=0;r<4;r++){
            const float mn = fmaxf(m[rg][r], tmr[rg][r]);
            const float al = __expf(m[rg][r] - mn);
            #pragma unroll
            for(int c=0;c<5;c++) o[rg][c][r] *= al;
            m[rg][r] = mn;
          }
      }
      // ---- exp + P write (sum comes free from the ones-column) ----
      #pragma unroll
      for(int rg=0;rg<2;rg++)
        #pragma unroll
        for(int r=0;r<4;r++){
          const int prow = rg*16 + quad*4 + r;
          #pragma unroll
          for(int c=0;c<4;c++){
            const float p = __expf(s[rg][c][r] - m[rg][r]);
            Pw[prow*64 + (((c*2 + (l16>>3)) ^ (prow&7))<<3) + (l16&7)] = f2bf(p);
          }
        }
      // ---- PV (c=4 is the ones-column): V frags shared across row-groups ----
      __builtin_amdgcn_s_setprio(1);
      #pragma unroll
      for(int kk=0;kk<2;kk++){
        short8 pf[2];
        #pragma unroll
        for(int rg=0;rg<2;rg++)
          pf[rg] = *(const short8*)&Pw[(rg*16 + l16)*64 + (((kk*4+quad) ^ (l16&7))<<3)];
        #pragma unroll
        for(int c=0;c<5;c++){
          const int dd = c*16 + l16;
          short8 vf = *(const short8*)&Vc[dd*64 + (((kk*4+quad)^(l16&7))<<3)];
          #pragma unroll
          for(int rg=0;rg<2;rg++)
            o[rg][c] = mfma16(pf[rg], vf, o[rg][c]);
        }
      }
      __builtin_amdgcn_s_setprio(0);
    }
    __builtin_amdgcn_s_barrier();      // raw: all waves done reading this buf
                                       // before next iter's prefetch overwrites it
  }
  #pragma unroll
  for(int rg=0;rg<2;rg++)
    #pragma unroll
    for(int r=0;r<4;r++){
      const float lr = __shfl(o[rg][4][r], quad<<4, 64);  // sum lives in l16==0
      const float il = 1.f / lr;
      const size_t row = (size_t)(b*T_ + qw + rg*16 + quad*4 + r);
      #pragma unroll
      for(int c=0;c<4;c++)
        ao[row*D_ + h*HD_ + c*16 + l16] = f2bf(o[rg][c][r] * il);
    }
}

extern "C" void kernel_launch(void* const* d_in, const int* in_sizes, int n_in,
                              void* d_out, int out_size, void* d_ws, size_t ws_size,
                              hipStream_t stream) {
  const int*   x    = (const int*)d_in[0];
  const float* emb  = (const float*)d_in[1];
  const float* wq   = (const float*)d_in[2];
  const float* wk   = (const float*)d_in[3];
  const float* wv   = (const float*)d_in[4];
  const float* wo   = (const float*)d_in[5];
  const float* ln1  = (const float*)d_in[6];
  const float* ln2  = (const float*)d_in[7];
  const float* w1   = (const float*)d_in[8];
  const float* b1   = (const float*)d_in[9];
  const float* w2   = (const float*)d_in[10];
  const float* b2   = (const float*)d_in[11];
  const float* lnf  = (const float*)d_in[12];
  const float* head = (const float*)d_in[13];
  float* out = (float*)d_out;

  char* ws = (char*)d_ws; size_t off = 0;
  auto alloc = [&](size_t bytes)->void* {
    void* p = ws + off; off += (bytes + 255) & ~(size_t)255; return p;
  };
  float* hbuf  = (float*)alloc((size_t)BT_*D_*4);
  u16* xn    = (u16*)alloc((size_t)BT_*D_*2);
  u16* qb    = (u16*)alloc((size_t)BT_*D_*2);
  u16* kb    = (u16*)alloc((size_t)BT_*D_*2);
  u16* vtb   = (u16*)alloc((size_t)BT_*D_*2);
  u16* aob   = (u16*)alloc((size_t)BT_*D_*2);
  u16* midb  = (u16*)alloc((size_t)BT_*HF_*2);
  u16* qkvt  = (u16*)alloc((size_t)L_*3*D_*D_*2);
  u16* wot   = (u16*)alloc((size_t)L_*D_*D_*2);
  u16* w1t   = (u16*)alloc((size_t)L_*HF_*D_*2);
  u16* w2t   = (u16*)alloc((size_t)L_*D_*HF_*2);
  u16* headt = (u16*)alloc((size_t)V_*D_*2);

  const dim3 blk(256);
  // weight transposes: dst[n][k] = src[k][n], coalesced both sides
  wtrans_kernel<<<dim3(D_/32, D_/32, L_), blk, 0, stream>>>(wq, qkvt,           D_, D_, (size_t)D_*D_, (size_t)3*D_*D_);
  wtrans_kernel<<<dim3(D_/32, D_/32, L_), blk, 0, stream>>>(wk, qkvt + D_*D_,   D_, D_, (size_t)D_*D_, (size_t)3*D_*D_);
  wtrans_kernel<<<dim3(D_/32, D_/32, L_), blk, 0, stream>>>(wv, qkvt + 2*D_*D_, D_, D_, (size_t)D_*D_, (size_t)3*D_*D_);
  wtrans_kernel<<<dim3(D_/32, D_/32, L_), blk, 0, stream>>>(wo, wot,            D_, D_, (size_t)D_*D_, (size_t)D_*D_);
  wtrans_kernel<<<dim3(HF_/32, D_/32, L_), blk, 0, stream>>>(w1, w1t, D_, HF_, (size_t)D_*HF_, (size_t)HF_*D_);
  wtrans_kernel<<<dim3(D_/32, HF_/32, L_), blk, 0, stream>>>(w2, w2t, HF_, D_, (size_t)D_*HF_, (size_t)D_*HF_);
  wtrans_kernel<<<dim3(V_/32, D_/32, 1),  blk, 0, stream>>>(head, headt, D_, V_, 0, 0);

  embed_kernel<<<(BT_*D_ + 255)/256, blk, 0, stream>>>(x, emb, hbuf);

  for(int li=0; li<L_; li++){
    rms_kernel<<<BT_/4, blk, 0, stream>>>(hbuf, ln1 + li*D_, xn);
    gemm_kernel<3,D_,128><<<dim3(3*D_/128, BT_/128), blk, 0, stream>>>(
        xn, qkvt + (size_t)li*3*D_*D_, 3*D_, nullptr, nullptr, nullptr, qb, kb, vtb, nullptr);
    flash_kernel<<<dim3(T_/128, B_*NH_), blk, 0, stream>>>(qb, kb, vtb, aob);
    gemm_kernel<2,D_,64><<<dim3(D_/64, BT_/128), blk, 0, stream>>>(
        aob, wot + (size_t)li*D_*D_, D_, nullptr, nullptr, hbuf, nullptr, nullptr, nullptr, nullptr);
    rms_kernel<<<BT_/4, blk, 0, stream>>>(hbuf, ln2 + li*D_, xn);
    gemm_kernel<1,D_,128><<<dim3(HF_/128, BT_/128), blk, 0, stream>>>(
        xn, w1t + (size_t)li*HF_*D_, HF_, b1 + li*HF_, midb, nullptr, nullptr, nullptr, nullptr, nullptr);
    if(li == 2)
      gemm_kernel<4,HF_,64><<<dim3(D_/64, BT_/128), blk, 0, stream>>>(
          midb, w2t + (size_t)li*D_*HF_, D_, b2 + li*D_, nullptr, hbuf, nullptr, nullptr, nullptr,
          out + (size_t)BT_*V_);
    else
      gemm_kernel<2,HF_,64><<<dim3(D_/64, BT_/128), blk, 0, stream>>>(
          midb, w2t + (size_t)li*D_*HF_, D_, b2 + li*D_, nullptr, hbuf, nullptr, nullptr, nullptr, nullptr);
  }
  rms_kernel<<<BT_/4, blk, 0, stream>>>(hbuf, lnf, xn);
  gemm_kernel<0,D_,128><<<dim3(V_/128, BT_/128), blk, 0, stream>>>(
      xn, headt, V_, nullptr, nullptr, out, nullptr, nullptr, nullptr, nullptr);
}

// Round 6
// 1113.387 us; speedup vs baseline: 1.1802x; 1.1802x over previous
//
#include <hip/hip_runtime.h>
#include <hip/hip_bf16.h>
#include <math.h>

#define L_  6
#define D_  384
#define NH_ 6
#define HD_ 64
#define HF_ 768
#define V_  4096
#define B_  4
#define T_  2048
#define BT_ (B_*T_)

typedef unsigned short u16;
typedef __attribute__((ext_vector_type(8))) short short8;
typedef __attribute__((ext_vector_type(4))) float f32x4;

__device__ __forceinline__ float bf2f(u16 u){
  union { unsigned int i; float f; } c; c.i = ((unsigned int)u)<<16; return c.f;
}
__device__ __forceinline__ u16 f2bf(float f){
  union { float f; unsigned int i; } c; c.f = f;
  unsigned int x = c.i;
  x += 0x7fffu + ((x>>16)&1u);
  return (u16)(x>>16);
}
__device__ __forceinline__ f32x4 mfma16(short8 a, short8 b, f32x4 c){
  return __builtin_amdgcn_mfma_f32_16x16x32_bf16(a,b,c,0,0,0);
}
// 16-lane max reduce on the VALU pipe (no ds_bpermute): xor1, xor2, xor7, xor15
template<int CTRL>
__device__ __forceinline__ float dppmax(float x){
  int v = __builtin_amdgcn_update_dpp(0, __builtin_bit_cast(int, x), CTRL, 0xf, 0xf, true);
  return fmaxf(x, __builtin_bit_cast(float, v));
}
__device__ __forceinline__ float rowmax16(float x){
  x = dppmax<0xB1>(x);   // quad_perm [1,0,3,2]  : xor 1
  x = dppmax<0x4E>(x);   // quad_perm [2,3,0,1]  : xor 2
  x = dppmax<0x141>(x);  // row_half_mirror      : xor 7
  x = dppmax<0x140>(x);  // row_mirror           : xor 15
  return x;
}
// async global->LDS, 16B per lane, LDS dest = base + lane*16 (wave-uniform base)
#define GLD16(gp, lp) __builtin_amdgcn_global_load_lds( \
    (const __attribute__((address_space(1))) void*)(gp), \
    (__attribute__((address_space(3))) void*)(lp), 16, 0, 0)

// ---------------- embedding gather ----------------
__global__ void embed_kernel(const int* __restrict__ x, const float* __restrict__ emb,
                             float* __restrict__ h){
  const int idx = blockIdx.x*256 + threadIdx.x;
  if(idx >= BT_*D_) return;
  const int t = idx / D_;
  const int d = idx - t*D_;
  h[idx] = emb[(size_t)x[t]*D_ + d];
}

// ---- coalesced LDS-tiled weight transpose+cast: dst[b][n][k]=bf16(src[b][k][n])
__global__ __launch_bounds__(256) void wtrans_kernel(const float* __restrict__ src,
    u16* __restrict__ dst, int K, int N, size_t srcBatch, size_t dstBatch){
  __shared__ float tile[32][33];
  src += (size_t)blockIdx.z*srcBatch;
  dst += (size_t)blockIdx.z*dstBatch;
  const int tx = threadIdx.x&31, ty = threadIdx.x>>5;
  const int n0 = blockIdx.x*32, k0 = blockIdx.y*32;
  #pragma unroll
  for(int j=0;j<4;j++)
    tile[ty+j*8][tx] = src[(size_t)(k0+ty+j*8)*N + n0+tx];
  __syncthreads();
  #pragma unroll
  for(int j=0;j<4;j++)
    dst[(size_t)(n0+ty+j*8)*K + k0+tx] = f2bf(tile[tx][ty+j*8]);
}

// ---------------- rmsnorm: one wave per row of 384 ----------------
__global__ __launch_bounds__(256) void rms_kernel(const float* __restrict__ h,
                                                  const float* __restrict__ w,
                                                  u16* __restrict__ out){
  const int wave = threadIdx.x>>6, lane = threadIdx.x&63;
  const size_t row = (size_t)blockIdx.x*4 + wave;
  const float* hr = h + row*D_;
  float v[6]; float ss = 0.f;
  #pragma unroll
  for(int i=0;i<6;i++){ v[i] = hr[lane + i*64]; ss += v[i]*v[i]; }
  #pragma unroll
  for(int o=1;o<64;o<<=1) ss += __shfl_xor(ss, o);
  const float rn = rsqrtf(ss*(1.f/D_) + 1e-6f);
  u16* orow = out + row*D_;
  #pragma unroll
  for(int i=0;i<6;i++) orow[lane+i*64] = f2bf(v[i]*rn*w[lane+i*64]);
}

// ---------------- MFMA GEMM: C[M,N] = A[M,K] @ Wt[N,K]^T ----------------
// Generalized tile <BM,BN> with 4 waves arranged WM x WN. BK=64,
// double-buffered global_load_lds staging into XOR-swizzled LDS: prefetch
// tile t+1 issued before computing tile t, counted s_waitcnt (never 0
// mid-loop), raw s_barriers. BM=64 variants double the grid (latency-bound
// regime: more blocks/CU is the lever; weights stay L2-resident).
// MODE: 0=f32 out, 1=bias+gelu bf16, 2=f32 resid +=, 3=QKV split
// (v transposed to [B,NH,HD,T]), 4=resid += AND copy to fout2.
template<int MODE, int K, int BM, int BN>
__global__ __launch_bounds__(256) void gemm_kernel(
    const u16* __restrict__ A, const u16* __restrict__ Wt, int N,
    const float* __restrict__ bias, u16* __restrict__ out, float* __restrict__ fout,
    u16* __restrict__ qo, u16* __restrict__ ko, u16* __restrict__ vo,
    float* __restrict__ fout2)
{
  __shared__ u16 As[2][BM*64];
  __shared__ u16 Bs[2][BN*64];
  constexpr int WM  = (BM==128) ? ((BN==128)?2:4) : ((BN==128)?1:2);
  constexpr int WN  = 4/WM;
  constexpr int MI  = (BM/WM)/16;
  constexpr int NI  = (BN/WN)/16;
  constexpr int NKT = K/64;
  constexpr int APW = (BM/8)/4;            // A 1KB-chunks per wave
  constexpr int BPW = (BN/8)/4;            // B 1KB-chunks per wave
  constexpr int VM  = APW + BPW;           // loads in flight per wave per stage

  const int w = threadIdx.x>>6, lane = threadIdx.x&63;
  const int l16 = lane&15, quad = lane>>4;
  const int r0 = blockIdx.y*BM, n0 = blockIdx.x*BN;
  const int mst = lane>>3;                 // row within 1KB wave-chunk (8 rows)
  const int cst = (lane&7) ^ (lane>>3);    // swizzled 16B-chunk index

  const int wrow = (w%WM)*(BM/WM);
  const int wcol = (w/WM)*(BN/WN);

  f32x4 acc[MI][NI];
  #pragma unroll
  for(int mi=0;mi<MI;mi++)
    #pragma unroll
    for(int ni=0;ni<NI;ni++){ acc[mi][ni][0]=0.f; acc[mi][ni][1]=0.f; acc[mi][ni][2]=0.f; acc[mi][ni][3]=0.f; }

  auto stage = [&](int kt, int bu){
    const int k0 = kt*64;
    #pragma unroll
    for(int i=0;i<APW;i++){
      const int j = w*APW+i;
      GLD16(A + (size_t)(r0+j*8+mst)*K + k0 + cst*8, &As[bu][j*512]);
    }
    #pragma unroll
    for(int i=0;i<BPW;i++){
      const int j = w*BPW+i;
      GLD16(Wt + (size_t)(n0+j*8+mst)*K + k0 + cst*8, &Bs[bu][j*512]);
    }
  };

  stage(0, 0);                             // prologue
  for(int kt=0; kt<NKT; kt++){
    const u16* Ac = As[kt&1];
    const u16* Bc = Bs[kt&1];
    if(kt+1 < NKT){
      stage(kt+1, (kt+1)&1);               // prefetch: lands under compute
      if constexpr(VM==8)      asm volatile("s_waitcnt vmcnt(8)" ::: "memory");
      else if constexpr(VM==6) asm volatile("s_waitcnt vmcnt(6)" ::: "memory");
      else                     asm volatile("s_waitcnt vmcnt(4)" ::: "memory");
    } else {
      asm volatile("s_waitcnt vmcnt(0)" ::: "memory");
    }
    __builtin_amdgcn_s_barrier();          // raw: no vmcnt(0) drain
    asm volatile("" ::: "memory");

    __builtin_amdgcn_s_setprio(1);
    #pragma unroll
    for(int ks=0;ks<2;ks++){
      short8 av[MI], bv[NI];
      #pragma unroll
      for(int mi=0;mi<MI;mi++){
        const int m = wrow + mi*16 + l16;
        av[mi] = *(const short8*)&Ac[m*64 + (((ks*4+quad)^(l16&7))*8)];
      }
      #pragma unroll
      for(int ni=0;ni<NI;ni++){
        const int n = wcol + ni*16 + l16;
        bv[ni] = *(const short8*)&Bc[n*64 + (((ks*4+quad)^(l16&7))*8)];
      }
      #pragma unroll
      for(int mi=0;mi<MI;mi++)
        #pragma unroll
        for(int ni=0;ni<NI;ni++)
          acc[mi][ni] = mfma16(av[mi], bv[ni], acc[mi][ni]);
    }
    __builtin_amdgcn_s_setprio(0);
    if(kt+1 < NKT){
      asm volatile("" ::: "memory");
      __builtin_amdgcn_s_barrier();        // all waves done reading buf kt&1
    }
  }

  #pragma unroll
  for(int mi=0;mi<MI;mi++){
    #pragma unroll
    for(int ni=0;ni<NI;ni++){
      const int col = n0 + wcol + ni*16 + l16;
      #pragma unroll
      for(int r=0;r<4;r++){
        const int row = r0 + wrow + mi*16 + quad*4 + r;
        float v = acc[mi][ni][r];
        if(MODE==0){
          fout[(size_t)row*N + col] = v;
        } else if(MODE==1){
          v += bias[col];
          v = 0.5f*v*(1.f + erff(v*0.70710678118f));
          out[(size_t)row*N + col] = f2bf(v);
        } else if(MODE==2){
          if(bias) v += bias[col];
          fout[(size_t)row*N + col] += v;
        } else if(MODE==4){
          v += bias[col];
          const float nv = fout[(size_t)row*N + col] + v;
          fout[(size_t)row*N + col] = nv;
          fout2[(size_t)row*N + col] = nv;
        } else {
          if(col < D_)        qo[(size_t)row*D_ + col]      = f2bf(v);
          else if(col < 2*D_) ko[(size_t)row*D_ + (col-D_)] = f2bf(v);
          else {
            const int cv = col - 2*D_;
            const int hh = cv>>6, dd = cv&63;
            const int bb = row>>11, tt = row&(T_-1);
            vo[(((size_t)(bb*NH_+hh))*HD_ + dd)*T_ + tt] = f2bf(v);
          }
        }
      }
    }
  }
}

// ---------------- causal flash attention ----------------
// grid (T/64, B*NH), 4 waves, 16 q rows/wave, KT=64 k-tiles.  (R3-verified
// config: 768 blocks, 3 blocks/CU, 12 waves/CU — the 128-q variant
// regressed by doubling the tail block's critical path at half the grid.)
// Double-buffered K/V, counted vmcnt(4), raw s_barriers. LDS = 45056 B.
// Row-sum free via ones-column in V^T (o[4]); row-max via DPP; T13
// defer-max (skip o-rescale while tile max <= m+8).
__global__ __launch_bounds__(256) void flash_kernel(const u16* __restrict__ q,
    const u16* __restrict__ k, const u16* __restrict__ vt, u16* __restrict__ ao){
  __shared__ u16 Ks[2][64*64];               // [buf][k][d]   8KB each
  __shared__ u16 Vs[2][80*64];               // [buf][d][k]  10KB each; rows 64..79 static
  __shared__ __align__(16) u16 Pb[4][16*64]; // per-wave P    2KB each
  const int tid = threadIdx.x;
  const int w = tid>>6, lane = tid&63;
  const int l16 = lane&15, quad = lane>>4;
  const int bh = blockIdx.y, b = bh/NH_, h = bh - b*NH_;
  const int qt = (gridDim.x-1) - blockIdx.x; // reversed: heavy blocks first
  const int qw = qt*64 + w*16;

  // init static V^T rows (row 64 = 1.0 -> PV computes row-sums in o[4];
  // rows 65..79 = 0). Written once per buffer, DMA never touches them.
  {
    const int idx0 = tid*8;
    #pragma unroll
    for(int i=0;i<8;i++){
      const int idx = idx0 + i;              // 0..2047
      const int bu = idx>>10, rem = idx&1023;
      Vs[bu][(64 + (rem>>6))*64 + (rem&63)] = ((rem>>6)==0) ? (u16)0x3F80 : (u16)0;
    }
  }
  __syncthreads();

  const u16* qp = q + ((size_t)(b*T_ + qw + l16))*D_ + h*HD_ + quad*8;
  short8 qf0 = *(const short8*)(qp);
  short8 qf1 = *(const short8*)(qp + 32);

  const u16* kbase = k + (size_t)(b*T_)*D_ + h*HD_;
  const u16* vbase = vt + (size_t)(b*NH_ + h)*HD_*T_;
  u16* Pw = &Pb[w][0];

  const int srow = lane>>3;            // row within 8-row 1KB chunk
  const int schunk = lane&7;           // dest 16B-chunk position in row
  const int kgc = schunk ^ srow;       // swizzled global source chunk

  float m[4];
  f32x4 o[5];                          // o[4] = running sum(exp) column
  #pragma unroll
  for(int r=0;r<4;r++) m[r] = -1e30f;
  #pragma unroll
  for(int c=0;c<5;c++){ o[c][0]=0.f; o[c][1]=0.f; o[c][2]=0.f; o[c][3]=0.f; }

  const int nkt = qt + 1;              // 64-wide tiles covering k <= qt*64+63

  // prologue: stage tile 0 into buffer 0 (4 loads/wave: 2 K + 2 V)
  #pragma unroll
  for(int i=0;i<2;i++){
    const int j = w*2+i;
    GLD16(kbase + (size_t)(j*8 + srow)*D_ + kgc*8, &Ks[0][j*512]);
  }
  #pragma unroll
  for(int i=0;i<2;i++){
    const int j = w*2+i;
    GLD16(vbase + (size_t)(j*8 + srow)*T_ + (schunk^srow)*8, &Vs[0][j*512]);
  }

  for(int kt=0; kt<nkt; kt++){
    const u16* Kc = Ks[kt&1];
    const u16* Vc = Vs[kt&1];
    if(kt+1 < nkt){
      // prefetch next tile into the other buffer (T14: issue-early)
      const int kb2 = (kt+1)*64;
      #pragma unroll
      for(int i=0;i<2;i++){
        const int j = w*2+i;
        GLD16(kbase + (size_t)(kb2 + j*8 + srow)*D_ + kgc*8, &Ks[(kt+1)&1][j*512]);
      }
      #pragma unroll
      for(int i=0;i<2;i++){
        const int j = w*2+i;
        GLD16(vbase + (size_t)(j*8 + srow)*T_ + kb2 + (schunk^srow)*8, &Vs[(kt+1)&1][j*512]);
      }
      // wait only this tile's 4 loads; the 4 prefetch loads stay in flight
      asm volatile("s_waitcnt vmcnt(4)" ::: "memory");
    } else {
      asm volatile("s_waitcnt vmcnt(0)" ::: "memory");
    }
    __builtin_amdgcn_s_barrier();      // raw: no vmcnt(0) drain

    // ---- QK^T ----
    float s[4][4];
    __builtin_amdgcn_s_setprio(1);
    #pragma unroll
    for(int c=0;c<4;c++){
      const int krow = c*16 + l16;
      short8 kf0 = *(const short8*)&Kc[krow*64 + ((quad^(l16&7))*8)];
      short8 kf1 = *(const short8*)&Kc[krow*64 + (((4+quad)^(l16&7))*8)];
      f32x4 sa = {0.f,0.f,0.f,0.f};
      sa = mfma16(qf0, kf0, sa);
      sa = mfma16(qf1, kf1, sa);
      #pragma unroll
      for(int r=0;r<4;r++) s[c][r] = sa[r]*0.125f;
    }
    __builtin_amdgcn_s_setprio(0);
    if(kt == nkt-1){
      const int kb = kt*64;
      #pragma unroll
      for(int c=0;c<4;c++){
        const int kpos = kb + c*16 + l16;
        #pragma unroll
        for(int r=0;r<4;r++)
          if(kpos > qw + quad*4 + r) s[c][r] = -1e30f;
      }
    }
    // ---- row max (DPP, VALU pipe) + deferred rescale ----
    float tmr[4];
    #pragma unroll
    for(int r=0;r<4;r++){
      float tm = fmaxf(fmaxf(s[0][r], s[1][r]), fmaxf(s[2][r], s[3][r]));
      tmr[r] = rowmax16(tm);
    }
    float need = tmr[0] - m[0];
    #pragma unroll
    for(int r=1;r<4;r++) need = fmaxf(need, tmr[r] - m[r]);
    if(!__all(need <= 8.f)){
      #pragma unroll
      for(int r=0;r<4;r++){
        const float mn = fmaxf(m[r], tmr[r]);
        const float al = __expf(m[r] - mn);
        #pragma unroll
        for(int c=0;c<5;c++) o[c][r] *= al;
        m[r] = mn;
      }
    }
    // ---- exp + P write (sum comes free from the ones-column) ----
    #pragma unroll
    for(int r=0;r<4;r++){
      const int prow = quad*4 + r;
      #pragma unroll
      for(int c=0;c<4;c++){
        const float p = __expf(s[c][r] - m[r]);
        // col c*16+l16 -> chunk (c*2 + l16>>3) XOR (prow&7)
        Pw[prow*64 + (((c*2 + (l16>>3)) ^ (prow&7))<<3) + (l16&7)] = f2bf(p);
      }
    }
    // ---- PV (c=4 is the ones-column -> o[4] += row sums) ----
    __builtin_amdgcn_s_setprio(1);
    #pragma unroll
    for(int kk=0;kk<2;kk++){
      short8 pf = *(const short8*)&Pw[l16*64 + (((kk*4+quad) ^ (l16&7))<<3)];
      #pragma unroll
      for(int c=0;c<5;c++){
        const int dd = c*16 + l16;
        short8 vf = *(const short8*)&Vc[dd*64 + (((kk*4+quad)^(l16&7))<<3)];
        o[c] = mfma16(pf, vf, o[c]);
      }
    }
    __builtin_amdgcn_s_setprio(0);
    __builtin_amdgcn_s_barrier();      // raw: all waves done reading this buf
                                       // before next iter's prefetch overwrites it
  }
  #pragma unroll
  for(int r=0;r<4;r++){
    const float lr = __shfl(o[4][r], quad<<4, 64);  // sum lives in lane l16==0
    const float il = 1.f / lr;
    const size_t row = (size_t)(b*T_ + qw + quad*4 + r);
    #pragma unroll
    for(int c=0;c<4;c++)
      ao[row*D_ + h*HD_ + c*16 + l16] = f2bf(o[c][r] * il);
  }
}

extern "C" void kernel_launch(void* const* d_in, const int* in_sizes, int n_in,
                              void* d_out, int out_size, void* d_ws, size_t ws_size,
                              hipStream_t stream) {
  const int*   x    = (const int*)d_in[0];
  const float* emb  = (const float*)d_in[1];
  const float* wq   = (const float*)d_in[2];
  const float* wk   = (const float*)d_in[3];
  const float* wv   = (const float*)d_in[4];
  const float* wo   = (const float*)d_in[5];
  const float* ln1  = (const float*)d_in[6];
  const float* ln2  = (const float*)d_in[7];
  const float* w1   = (const float*)d_in[8];
  const float* b1   = (const float*)d_in[9];
  const float* w2   = (const float*)d_in[10];
  const float* b2   = (const float*)d_in[11];
  const float* lnf  = (const float*)d_in[12];
  const float* head = (const float*)d_in[13];
  float* out = (float*)d_out;

  char* ws = (char*)d_ws; size_t off = 0;
  auto alloc = [&](size_t bytes)->void* {
    void* p = ws + off; off += (bytes + 255) & ~(size_t)255; return p;
  };
  float* hbuf  = (float*)alloc((size_t)BT_*D_*4);
  u16* xn    = (u16*)alloc((size_t)BT_*D_*2);
  u16* qb    = (u16*)alloc((size_t)BT_*D_*2);
  u16* kb    = (u16*)alloc((size_t)BT_*D_*2);
  u16* vtb   = (u16*)alloc((size_t)BT_*D_*2);
  u16* aob   = (u16*)alloc((size_t)BT_*D_*2);
  u16* midb  = (u16*)alloc((size_t)BT_*HF_*2);
  u16* qkvt  = (u16*)alloc((size_t)L_*3*D_*D_*2);
  u16* wot   = (u16*)alloc((size_t)L_*D_*D_*2);
  u16* w1t   = (u16*)alloc((size_t)L_*HF_*D_*2);
  u16* w2t   = (u16*)alloc((size_t)L_*D_*HF_*2);
  u16* headt = (u16*)alloc((size_t)V_*D_*2);

  const dim3 blk(256);
  // weight transposes: dst[n][k] = src[k][n], coalesced both sides
  wtrans_kernel<<<dim3(D_/32, D_/32, L_), blk, 0, stream>>>(wq, qkvt,           D_, D_, (size_t)D_*D_, (size_t)3*D_*D_);
  wtrans_kernel<<<dim3(D_/32, D_/32, L_), blk, 0, stream>>>(wk, qkvt + D_*D_,   D_, D_, (size_t)D_*D_, (size_t)3*D_*D_);
  wtrans_kernel<<<dim3(D_/32, D_/32, L_), blk, 0, stream>>>(wv, qkvt + 2*D_*D_, D_, D_, (size_t)D_*D_, (size_t)3*D_*D_);
  wtrans_kernel<<<dim3(D_/32, D_/32, L_), blk, 0, stream>>>(wo, wot,            D_, D_, (size_t)D_*D_, (size_t)D_*D_);
  wtrans_kernel<<<dim3(HF_/32, D_/32, L_), blk, 0, stream>>>(w1, w1t, D_, HF_, (size_t)D_*HF_, (size_t)HF_*D_);
  wtrans_kernel<<<dim3(D_/32, HF_/32, L_), blk, 0, stream>>>(w2, w2t, HF_, D_, (size_t)D_*HF_, (size_t)D_*HF_);
  wtrans_kernel<<<dim3(V_/32, D_/32, 1),  blk, 0, stream>>>(head, headt, D_, V_, 0, 0);

  embed_kernel<<<(BT_*D_ + 255)/256, blk, 0, stream>>>(x, emb, hbuf);

  for(int li=0; li<L_; li++){
    rms_kernel<<<BT_/4, blk, 0, stream>>>(hbuf, ln1 + li*D_, xn);
    gemm_kernel<3,D_,64,128><<<dim3(3*D_/128, BT_/64), blk, 0, stream>>>(
        xn, qkvt + (size_t)li*3*D_*D_, 3*D_, nullptr, nullptr, nullptr, qb, kb, vtb, nullptr);
    flash_kernel<<<dim3(T_/64, B_*NH_), blk, 0, stream>>>(qb, kb, vtb, aob);
    gemm_kernel<2,D_,64,64><<<dim3(D_/64, BT_/64), blk, 0, stream>>>(
        aob, wot + (size_t)li*D_*D_, D_, nullptr, nullptr, hbuf, nullptr, nullptr, nullptr, nullptr);
    rms_kernel<<<BT_/4, blk, 0, stream>>>(hbuf, ln2 + li*D_, xn);
    gemm_kernel<1,D_,64,128><<<dim3(HF_/128, BT_/64), blk, 0, stream>>>(
        xn, w1t + (size_t)li*HF_*D_, HF_, b1 + li*HF_, midb, nullptr, nullptr, nullptr, nullptr, nullptr);
    if(li == 2)
      gemm_kernel<4,HF_,64,64><<<dim3(D_/64, BT_/64), blk, 0, stream>>>(
          midb, w2t + (size_t)li*D_*HF_, D_, b2 + li*D_, nullptr, hbuf, nullptr, nullptr, nullptr,
          out + (size_t)BT_*V_);
    else
      gemm_kernel<2,HF_,64,64><<<dim3(D_/64, BT_/64), blk, 0, stream>>>(
          midb, w2t + (size_t)li*D_*HF_, D_, b2 + li*D_, nullptr, hbuf, nullptr, nullptr, nullptr, nullptr);
  }
  rms_kernel<<<BT_/4, blk, 0, stream>>>(hbuf, lnf, xn);
  gemm_kernel<0,D_,64,128><<<dim3(V_/128, BT_/64), blk, 0, stream>>>(
      xn, headt, V_, nullptr, nullptr, out, nullptr, nullptr, nullptr, nullptr);
}

// Round 7
// 1041.755 us; speedup vs baseline: 1.2613x; 1.0688x over previous
//
#include <hip/hip_runtime.h>
#include <hip/hip_bf16.h>
#include <math.h>

#define L_  6
#define D_  384
#define NH_ 6
#define HD_ 64
#define HF_ 768
#define V_  4096
#define B_  4
#define T_  2048
#define BT_ (B_*T_)

typedef unsigned short u16;
typedef __attribute__((ext_vector_type(8))) short short8;
typedef __attribute__((ext_vector_type(4))) float f32x4;
typedef __attribute__((ext_vector_type(4))) int   int4v;

__device__ __forceinline__ float bf2f(u16 u){
  union { unsigned int i; float f; } c; c.i = ((unsigned int)u)<<16; return c.f;
}
__device__ __forceinline__ u16 f2bf(float f){
  union { float f; unsigned int i; } c; c.f = f;
  unsigned int x = c.i;
  x += 0x7fffu + ((x>>16)&1u);
  return (u16)(x>>16);
}
__device__ __forceinline__ f32x4 mfma16(short8 a, short8 b, f32x4 c){
  return __builtin_amdgcn_mfma_f32_16x16x32_bf16(a,b,c,0,0,0);
}
// raw 2^x on the trans pipe
__device__ __forceinline__ float exp2a(float x){
  float r; asm("v_exp_f32 %0, %1" : "=v"(r) : "v"(x)); return r;
}
// pack two f32 -> 2x bf16 (lo = first arg), RNE
__device__ __forceinline__ int cvtpkbf(float lo, float hi){
  int r; asm("v_cvt_pk_bf16_f32 %0, %1, %2" : "=v"(r) : "v"(lo), "v"(hi)); return r;
}
// a.hi32 <-> b.lo32 ; after: a=[a.lo,b.lo], b=[a.hi,b.hi]
__device__ __forceinline__ void pl32(int &a, int &b){
  asm("v_permlane32_swap_b32 %0, %1" : "+v"(a), "+v"(b));
}
// a.row1<->b.row0, a.row3<->b.row2 (16-lane rows); after: a=[a0,b0,a2,b2], b=[a1,b1,a3,b3]
__device__ __forceinline__ void pl16(int &a, int &b){
  asm("v_permlane16_swap_b32 %0, %1" : "+v"(a), "+v"(b));
}
// async global->LDS, 16B per lane, LDS dest = base + lane*16 (wave-uniform base)
#define GLD16(gp, lp) __builtin_amdgcn_global_load_lds( \
    (const __attribute__((address_space(1))) void*)(gp), \
    (__attribute__((address_space(3))) void*)(lp), 16, 0, 0)

// ---------------- embedding gather ----------------
__global__ void embed_kernel(const int* __restrict__ x, const float* __restrict__ emb,
                             float* __restrict__ h){
  const int idx = blockIdx.x*256 + threadIdx.x;
  if(idx >= BT_*D_) return;
  const int t = idx / D_;
  const int d = idx - t*D_;
  h[idx] = emb[(size_t)x[t]*D_ + d];
}

// ---- coalesced LDS-tiled weight transpose+cast: dst[b][n][k]=bf16(src[b][k][n])
__global__ __launch_bounds__(256) void wtrans_kernel(const float* __restrict__ src,
    u16* __restrict__ dst, int K, int N, size_t srcBatch, size_t dstBatch){
  __shared__ float tile[32][33];
  src += (size_t)blockIdx.z*srcBatch;
  dst += (size_t)blockIdx.z*dstBatch;
  const int tx = threadIdx.x&31, ty = threadIdx.x>>5;
  const int n0 = blockIdx.x*32, k0 = blockIdx.y*32;
  #pragma unroll
  for(int j=0;j<4;j++)
    tile[ty+j*8][tx] = src[(size_t)(k0+ty+j*8)*N + n0+tx];
  __syncthreads();
  #pragma unroll
  for(int j=0;j<4;j++)
    dst[(size_t)(n0+ty+j*8)*K + k0+tx] = f2bf(tile[tx][ty+j*8]);
}

// ---------------- rmsnorm: one wave per row of 384 ----------------
__global__ __launch_bounds__(256) void rms_kernel(const float* __restrict__ h,
                                                  const float* __restrict__ w,
                                                  u16* __restrict__ out){
  const int wave = threadIdx.x>>6, lane = threadIdx.x&63;
  const size_t row = (size_t)blockIdx.x*4 + wave;
  const float* hr = h + row*D_;
  float v[6]; float ss = 0.f;
  #pragma unroll
  for(int i=0;i<6;i++){ v[i] = hr[lane + i*64]; ss += v[i]*v[i]; }
  #pragma unroll
  for(int o=1;o<64;o<<=1) ss += __shfl_xor(ss, o);
  const float rn = rsqrtf(ss*(1.f/D_) + 1e-6f);
  u16* orow = out + row*D_;
  #pragma unroll
  for(int i=0;i<6;i++) orow[lane+i*64] = f2bf(v[i]*rn*w[lane+i*64]);
}

// ---------------- MFMA GEMM: C[M,N] = A[M,K] @ Wt[N,K]^T ----------------
// Generalized tile <BM,BN> with 4 waves arranged WM x WN. BK=64,
// double-buffered global_load_lds staging into XOR-swizzled LDS: prefetch
// tile t+1 issued before computing tile t, counted s_waitcnt (never 0
// mid-loop), raw s_barriers. BM=64 variants double the grid (latency-bound
// regime: more blocks/CU is the lever; weights stay L2-resident).
// MODE: 0=f32 out, 1=bias+gelu bf16, 2=f32 resid +=, 3=QKV split
// (v transposed to [B,NH,HD,T]), 4=resid += AND copy to fout2.
template<int MODE, int K, int BM, int BN>
__global__ __launch_bounds__(256) void gemm_kernel(
    const u16* __restrict__ A, const u16* __restrict__ Wt, int N,
    const float* __restrict__ bias, u16* __restrict__ out, float* __restrict__ fout,
    u16* __restrict__ qo, u16* __restrict__ ko, u16* __restrict__ vo,
    float* __restrict__ fout2)
{
  __shared__ u16 As[2][BM*64];
  __shared__ u16 Bs[2][BN*64];
  constexpr int WM  = (BM==128) ? ((BN==128)?2:4) : ((BN==128)?1:2);
  constexpr int WN  = 4/WM;
  constexpr int MI  = (BM/WM)/16;
  constexpr int NI  = (BN/WN)/16;
  constexpr int NKT = K/64;
  constexpr int APW = (BM/8)/4;            // A 1KB-chunks per wave
  constexpr int BPW = (BN/8)/4;            // B 1KB-chunks per wave
  constexpr int VM  = APW + BPW;           // loads in flight per wave per stage

  const int w = threadIdx.x>>6, lane = threadIdx.x&63;
  const int l16 = lane&15, quad = lane>>4;
  const int r0 = blockIdx.y*BM, n0 = blockIdx.x*BN;
  const int mst = lane>>3;                 // row within 1KB wave-chunk (8 rows)
  const int cst = (lane&7) ^ (lane>>3);    // swizzled 16B-chunk index

  const int wrow = (w%WM)*(BM/WM);
  const int wcol = (w/WM)*(BN/WN);

  f32x4 acc[MI][NI];
  #pragma unroll
  for(int mi=0;mi<MI;mi++)
    #pragma unroll
    for(int ni=0;ni<NI;ni++){ acc[mi][ni][0]=0.f; acc[mi][ni][1]=0.f; acc[mi][ni][2]=0.f; acc[mi][ni][3]=0.f; }

  auto stage = [&](int kt, int bu){
    const int k0 = kt*64;
    #pragma unroll
    for(int i=0;i<APW;i++){
      const int j = w*APW+i;
      GLD16(A + (size_t)(r0+j*8+mst)*K + k0 + cst*8, &As[bu][j*512]);
    }
    #pragma unroll
    for(int i=0;i<BPW;i++){
      const int j = w*BPW+i;
      GLD16(Wt + (size_t)(n0+j*8+mst)*K + k0 + cst*8, &Bs[bu][j*512]);
    }
  };

  stage(0, 0);                             // prologue
  for(int kt=0; kt<NKT; kt++){
    const u16* Ac = As[kt&1];
    const u16* Bc = Bs[kt&1];
    if(kt+1 < NKT){
      stage(kt+1, (kt+1)&1);               // prefetch: lands under compute
      if constexpr(VM==8)      asm volatile("s_waitcnt vmcnt(8)" ::: "memory");
      else if constexpr(VM==6) asm volatile("s_waitcnt vmcnt(6)" ::: "memory");
      else                     asm volatile("s_waitcnt vmcnt(4)" ::: "memory");
    } else {
      asm volatile("s_waitcnt vmcnt(0)" ::: "memory");
    }
    __builtin_amdgcn_s_barrier();          // raw: no vmcnt(0) drain
    asm volatile("" ::: "memory");

    __builtin_amdgcn_s_setprio(1);
    #pragma unroll
    for(int ks=0;ks<2;ks++){
      short8 av[MI], bv[NI];
      #pragma unroll
      for(int mi=0;mi<MI;mi++){
        const int m = wrow + mi*16 + l16;
        av[mi] = *(const short8*)&Ac[m*64 + (((ks*4+quad)^(l16&7))*8)];
      }
      #pragma unroll
      for(int ni=0;ni<NI;ni++){
        const int n = wcol + ni*16 + l16;
        bv[ni] = *(const short8*)&Bc[n*64 + (((ks*4+quad)^(l16&7))*8)];
      }
      #pragma unroll
      for(int mi=0;mi<MI;mi++)
        #pragma unroll
        for(int ni=0;ni<NI;ni++)
          acc[mi][ni] = mfma16(av[mi], bv[ni], acc[mi][ni]);
    }
    __builtin_amdgcn_s_setprio(0);
    if(kt+1 < NKT){
      asm volatile("" ::: "memory");
      __builtin_amdgcn_s_barrier();        // all waves done reading buf kt&1
    }
  }

  #pragma unroll
  for(int mi=0;mi<MI;mi++){
    #pragma unroll
    for(int ni=0;ni<NI;ni++){
      const int col = n0 + wcol + ni*16 + l16;
      #pragma unroll
      for(int r=0;r<4;r++){
        const int row = r0 + wrow + mi*16 + quad*4 + r;
        float v = acc[mi][ni][r];
        if(MODE==0){
          fout[(size_t)row*N + col] = v;
        } else if(MODE==1){
          v += bias[col];
          v = 0.5f*v*(1.f + erff(v*0.70710678118f));
          out[(size_t)row*N + col] = f2bf(v);
        } else if(MODE==2){
          if(bias) v += bias[col];
          fout[(size_t)row*N + col] += v;
        } else if(MODE==4){
          v += bias[col];
          const float nv = fout[(size_t)row*N + col] + v;
          fout[(size_t)row*N + col] = nv;
          fout2[(size_t)row*N + col] = nv;
        } else {
          if(col < D_)        qo[(size_t)row*D_ + col]      = f2bf(v);
          else if(col < 2*D_) ko[(size_t)row*D_ + (col-D_)] = f2bf(v);
          else {
            const int cv = col - 2*D_;
            const int hh = cv>>6, dd = cv&63;
            const int bb = row>>11, tt = row&(T_-1);
            vo[(((size_t)(bb*NH_+hh))*HD_ + dd)*T_ + tt] = f2bf(v);
          }
        }
      }
    }
  }
}

// ---------------- causal flash attention (swapped-QK, in-register P) ----
// grid (T/64, B*NH), 4 waves, 16 q rows/wave (q = qw + l16), KT=64.
// QK^T computed swapped: s = mfma(K,Q) -> lane holds S^T[k][q=l16] with
// k = c*16 + quad*4 + r. Softmax per-lane (m is a per-lane scalar, log2
// domain, exp2 on trans pipe); defer-max threshold 11.5 (=8 nats).
// P never touches LDS: cvt_pk_bf16 pairs + permlane32/16_swap rebuild the
// PV B-fragment in-register. PV = mfma(V^T, P^T) -> O^T; ones-row 64 of
// V^T accumulates the softmax denominator for free (lane quad0/reg0).
// Double-buffered K/V staging, counted vmcnt(4), raw s_barriers.
// Epilogue: one-time per-wave LDS transpose (reuses Ks, stride 72 u16,
// 2-way bank aliasing = free) for coalesced 16B output stores.
// LDS = 36864 B.
__global__ __launch_bounds__(256) void flash_kernel(const u16* __restrict__ q,
    const u16* __restrict__ k, const u16* __restrict__ vt, u16* __restrict__ ao){
  __shared__ u16 Ks[2][64*64];               // [buf][k][d]   8KB each
  __shared__ u16 Vs[2][80*64];               // [buf][d][k]  10KB each; rows 64..79 static
  const int tid = threadIdx.x;
  const int w = tid>>6, lane = tid&63;
  const int l16 = lane&15, quad = lane>>4;
  const bool hi32 = lane >= 32;              // quad>>1 == 1
  const int bh = blockIdx.y, b = bh/NH_, h = bh - b*NH_;
  const int qt = (gridDim.x-1) - blockIdx.x; // reversed: heavy blocks first
  const int qw = qt*64 + w*16;

  // init static V^T rows (row 64 = 1.0 -> PV accumulates sum(exp);
  // rows 65..79 = 0). Written once per buffer, DMA never touches them.
  {
    const int idx0 = tid*8;
    #pragma unroll
    for(int i=0;i<8;i++){
      const int idx = idx0 + i;              // 0..2047
      const int bu = idx>>10, rem = idx&1023;
      Vs[bu][(64 + (rem>>6))*64 + (rem&63)] = ((rem>>6)==0) ? (u16)0x3F80 : (u16)0;
    }
  }
  __syncthreads();

  const u16* qp = q + ((size_t)(b*T_ + qw + l16))*D_ + h*HD_ + quad*8;
  short8 qf0 = *(const short8*)(qp);
  short8 qf1 = *(const short8*)(qp + 32);

  const u16* kbase = k + (size_t)(b*T_)*D_ + h*HD_;
  const u16* vbase = vt + (size_t)(b*NH_ + h)*HD_*T_;

  const int srow = lane>>3;            // row within 8-row 1KB chunk
  const int schunk = lane&7;           // dest 16B-chunk position in row
  const int kgc = schunk ^ srow;       // swizzled global source chunk

  const float sc2 = 0.18033688011112042f;   // 0.125 * log2(e)
  float m2 = -1e30f;                   // running max, log2 domain, per-lane q
  f32x4 o[5];                          // o[c2][r] = O^T[d=c2*16+quad*4+r][q]
  #pragma unroll
  for(int c=0;c<5;c++){ o[c][0]=0.f; o[c][1]=0.f; o[c][2]=0.f; o[c][3]=0.f; }

  const int nkt = qt + 1;              // 64-wide tiles covering k <= qt*64+63

  // prologue: stage tile 0 into buffer 0 (4 loads/wave: 2 K + 2 V)
  #pragma unroll
  for(int i=0;i<2;i++){
    const int j = w*2+i;
    GLD16(kbase + (size_t)(j*8 + srow)*D_ + kgc*8, &Ks[0][j*512]);
  }
  #pragma unroll
  for(int i=0;i<2;i++){
    const int j = w*2+i;
    GLD16(vbase + (size_t)(j*8 + srow)*T_ + (schunk^srow)*8, &Vs[0][j*512]);
  }

  for(int kt=0; kt<nkt; kt++){
    const u16* Kc = Ks[kt&1];
    const u16* Vc = Vs[kt&1];
    if(kt+1 < nkt){
      // prefetch next tile into the other buffer (T14: issue-early)
      const int kb2 = (kt+1)*64;
      #pragma unroll
      for(int i=0;i<2;i++){
        const int j = w*2+i;
        GLD16(kbase + (size_t)(kb2 + j*8 + srow)*D_ + kgc*8, &Ks[(kt+1)&1][j*512]);
      }
      #pragma unroll
      for(int i=0;i<2;i++){
        const int j = w*2+i;
        GLD16(vbase + (size_t)(j*8 + srow)*T_ + kb2 + (schunk^srow)*8, &Vs[(kt+1)&1][j*512]);
      }
      // wait only this tile's 4 loads; the 4 prefetch loads stay in flight
      asm volatile("s_waitcnt vmcnt(4)" ::: "memory");
    } else {
      asm volatile("s_waitcnt vmcnt(0)" ::: "memory");
    }
    __builtin_amdgcn_s_barrier();      // raw: no vmcnt(0) drain

    // ---- QK^T swapped: s[c][r] = S^T[k=c*16+quad*4+r][q=l16] (log2 units)
    float s[4][4];
    __builtin_amdgcn_s_setprio(1);
    #pragma unroll
    for(int c=0;c<4;c++){
      const int krow = c*16 + l16;
      short8 kf0 = *(const short8*)&Kc[krow*64 + ((quad^(l16&7))*8)];
      short8 kf1 = *(const short8*)&Kc[krow*64 + (((4+quad)^(l16&7))*8)];
      f32x4 sa = {0.f,0.f,0.f,0.f};
      sa = mfma16(kf0, qf0, sa);
      sa = mfma16(kf1, qf1, sa);
      #pragma unroll
      for(int r=0;r<4;r++) s[c][r] = sa[r]*sc2;
    }
    __builtin_amdgcn_s_setprio(0);
    if(kt == nkt-1){
      const int kb = kt*64;
      #pragma unroll
      for(int c=0;c<4;c++)
        #pragma unroll
        for(int r=0;r<4;r++){
          const int kpos = kb + c*16 + quad*4 + r;
          if(kpos > qw + l16) s[c][r] = -1e30f;
        }
    }
    // ---- per-lane partial max + deferred rescale ----
    float tm = s[0][0];
    #pragma unroll
    for(int c=0;c<4;c++)
      #pragma unroll
      for(int r=0;r<4;r++) tm = fmaxf(tm, s[c][r]);
    if(!__all(tm - m2 <= 11.5f)){
      float t = fmaxf(tm, __shfl_xor(tm, 16));
      t = fmaxf(t, __shfl_xor(t, 32));      // full max over k for this q
      const float mn = fmaxf(m2, t);
      const float al = exp2a(m2 - mn);
      #pragma unroll
      for(int c=0;c<5;c++)
        #pragma unroll
        for(int r=0;r<4;r++) o[c][r] *= al;
      m2 = mn;
    }
    // ---- exp2 + pack pairs (P stays in registers) ----
    int P01[4], P23[4];
    #pragma unroll
    for(int c=0;c<4;c++){
      const float p0 = exp2a(s[c][0] - m2);
      const float p1 = exp2a(s[c][1] - m2);
      const float p2 = exp2a(s[c][2] - m2);
      const float p3 = exp2a(s[c][3] - m2);
      P01[c] = cvtpkbf(p0, p1);
      P23[c] = cvtpkbf(p2, p3);
    }
    // ---- PV: O^T += V^T @ P^T; B-fragment built via permlane swaps ----
    __builtin_amdgcn_s_setprio(1);
    #pragma unroll
    for(int kk=0;kk<2;kk++){
      // M0(Z)=[Zq0,Zq2,Zq0,Zq2], M1(Z)=[Zq1,Zq3,Zq1,Zq3] per 16-rows
      int xA = P01[kk*2],   xB = xA; pl32(xA,xB); pl16(xA,xB);
      int yA = P01[kk*2+1], yB = yA; pl32(yA,yB); pl16(yA,yB);
      int zA = P23[kk*2],   zB = zA; pl32(zA,zB); pl16(zA,zB);
      int wA = P23[kk*2+1], wB = wA; pl32(wA,wB); pl16(wA,wB);
      // dest lane (quad=2a+b): word j-pair sources quad 2b (M0) / 2b+1 (M1),
      // reg c = kk*2 + a  (a=1 <=> lane>=32)
      int4v bi;
      bi.x = hi32 ? yA : xA;   // k = kk*32+quad*8+{0,1}
      bi.y = hi32 ? wA : zA;   // +{2,3}
      bi.z = hi32 ? yB : xB;   // +{4,5}
      bi.w = hi32 ? wB : zB;   // +{6,7}
      const short8 pb = __builtin_bit_cast(short8, bi);
      #pragma unroll
      for(int c2=0;c2<5;c2++){
        const int dd = c2*16 + l16;
        short8 vf = *(const short8*)&Vc[dd*64 + (((kk*4+quad)^(l16&7))<<3)];
        o[c2] = mfma16(vf, pb, o[c2]);
      }
    }
    __builtin_amdgcn_s_setprio(0);
    __builtin_amdgcn_s_barrier();      // raw: all waves done reading this buf
                                       // before next iter's prefetch overwrites it
  }

  // ---- epilogue: denominator broadcast, transpose via LDS, coalesced store
  const float sum = __shfl(o[4][0], l16, 64);   // lives at (l16, quad0), reg 0
  const float il = 1.f / sum;
  u16* Tb = &Ks[0][0] + w*1152;        // per-wave [16 q][64 d], stride 72 u16
  #pragma unroll
  for(int c2=0;c2<4;c2++){
    const int d01 = cvtpkbf(o[c2][0]*il, o[c2][1]*il);
    const int d23 = cvtpkbf(o[c2][2]*il, o[c2][3]*il);
    *(int*)&Tb[l16*72 + c2*16 + quad*4]     = d01;
    *(int*)&Tb[l16*72 + c2*16 + quad*4 + 2] = d23;
  }
  const short8 r0 = *(const short8*)&Tb[l16*72 + quad*8];
  const short8 r1 = *(const short8*)&Tb[l16*72 + (quad+4)*8];
  u16* aop = ao + (size_t)(b*T_ + qw + l16)*D_ + h*HD_;
  *(short8*)&aop[quad*8]     = r0;
  *(short8*)&aop[(quad+4)*8] = r1;
}

extern "C" void kernel_launch(void* const* d_in, const int* in_sizes, int n_in,
                              void* d_out, int out_size, void* d_ws, size_t ws_size,
                              hipStream_t stream) {
  const int*   x    = (const int*)d_in[0];
  const float* emb  = (const float*)d_in[1];
  const float* wq   = (const float*)d_in[2];
  const float* wk   = (const float*)d_in[3];
  const float* wv   = (const float*)d_in[4];
  const float* wo   = (const float*)d_in[5];
  const float* ln1  = (const float*)d_in[6];
  const float* ln2  = (const float*)d_in[7];
  const float* w1   = (const float*)d_in[8];
  const float* b1   = (const float*)d_in[9];
  const float* w2   = (const float*)d_in[10];
  const float* b2   = (const float*)d_in[11];
  const float* lnf  = (const float*)d_in[12];
  const float* head = (const float*)d_in[13];
  float* out = (float*)d_out;

  char* ws = (char*)d_ws; size_t off = 0;
  auto alloc = [&](size_t bytes)->void* {
    void* p = ws + off; off += (bytes + 255) & ~(size_t)255; return p;
  };
  float* hbuf  = (float*)alloc((size_t)BT_*D_*4);
  u16* xn    = (u16*)alloc((size_t)BT_*D_*2);
  u16* qb    = (u16*)alloc((size_t)BT_*D_*2);
  u16* kb    = (u16*)alloc((size_t)BT_*D_*2);
  u16* vtb   = (u16*)alloc((size_t)BT_*D_*2);
  u16* aob   = (u16*)alloc((size_t)BT_*D_*2);
  u16* midb  = (u16*)alloc((size_t)BT_*HF_*2);
  u16* qkvt  = (u16*)alloc((size_t)L_*3*D_*D_*2);
  u16* wot   = (u16*)alloc((size_t)L_*D_*D_*2);
  u16* w1t   = (u16*)alloc((size_t)L_*HF_*D_*2);
  u16* w2t   = (u16*)alloc((size_t)L_*D_*HF_*2);
  u16* headt = (u16*)alloc((size_t)V_*D_*2);

  const dim3 blk(256);
  // weight transposes: dst[n][k] = src[k][n], coalesced both sides
  wtrans_kernel<<<dim3(D_/32, D_/32, L_), blk, 0, stream>>>(wq, qkvt,           D_, D_, (size_t)D_*D_, (size_t)3*D_*D_);
  wtrans_kernel<<<dim3(D_/32, D_/32, L_), blk, 0, stream>>>(wk, qkvt + D_*D_,   D_, D_, (size_t)D_*D_, (size_t)3*D_*D_);
  wtrans_kernel<<<dim3(D_/32, D_/32, L_), blk, 0, stream>>>(wv, qkvt + 2*D_*D_, D_, D_, (size_t)D_*D_, (size_t)3*D_*D_);
  wtrans_kernel<<<dim3(D_/32, D_/32, L_), blk, 0, stream>>>(wo, wot,            D_, D_, (size_t)D_*D_, (size_t)D_*D_);
  wtrans_kernel<<<dim3(HF_/32, D_/32, L_), blk, 0, stream>>>(w1, w1t, D_, HF_, (size_t)D_*HF_, (size_t)HF_*D_);
  wtrans_kernel<<<dim3(D_/32, HF_/32, L_), blk, 0, stream>>>(w2, w2t, HF_, D_, (size_t)D_*HF_, (size_t)D_*HF_);
  wtrans_kernel<<<dim3(V_/32, D_/32, 1),  blk, 0, stream>>>(head, headt, D_, V_, 0, 0);

  embed_kernel<<<(BT_*D_ + 255)/256, blk, 0, stream>>>(x, emb, hbuf);

  for(int li=0; li<L_; li++){
    rms_kernel<<<BT_/4, blk, 0, stream>>>(hbuf, ln1 + li*D_, xn);
    gemm_kernel<3,D_,64,128><<<dim3(3*D_/128, BT_/64), blk, 0, stream>>>(
        xn, qkvt + (size_t)li*3*D_*D_, 3*D_, nullptr, nullptr, nullptr, qb, kb, vtb, nullptr);
    flash_kernel<<<dim3(T_/64, B_*NH_), blk, 0, stream>>>(qb, kb, vtb, aob);
    gemm_kernel<2,D_,64,64><<<dim3(D_/64, BT_/64), blk, 0, stream>>>(
        aob, wot + (size_t)li*D_*D_, D_, nullptr, nullptr, hbuf, nullptr, nullptr, nullptr, nullptr);
    rms_kernel<<<BT_/4, blk, 0, stream>>>(hbuf, ln2 + li*D_, xn);
    gemm_kernel<1,D_,64,128><<<dim3(HF_/128, BT_/64), blk, 0, stream>>>(
        xn, w1t + (size_t)li*HF_*D_, HF_, b1 + li*HF_, midb, nullptr, nullptr, nullptr, nullptr, nullptr);
    if(li == 2)
      gemm_kernel<4,HF_,64,64><<<dim3(D_/64, BT_/64), blk, 0, stream>>>(
          midb, w2t + (size_t)li*D_*HF_, D_, b2 + li*D_, nullptr, hbuf, nullptr, nullptr, nullptr,
          out + (size_t)BT_*V_);
    else
      gemm_kernel<2,HF_,64,64><<<dim3(D_/64, BT_/64), blk, 0, stream>>>(
          midb, w2t + (size_t)li*D_*HF_, D_, b2 + li*D_, nullptr, hbuf, nullptr, nullptr, nullptr, nullptr);
  }
  rms_kernel<<<BT_/4, blk, 0, stream>>>(hbuf, lnf, xn);
  gemm_kernel<0,D_,64,128><<<dim3(V_/128, BT_/64), blk, 0, stream>>>(
      xn, headt, V_, nullptr, nullptr, out, nullptr, nullptr, nullptr, nullptr);
}